// Round 7
// baseline (1037.050 us; speedup 1.0000x reference)
//
#include <hip/hip_runtime.h>
#include <hip/hip_bf16.h>

namespace {

constexpr int H      = 256;  // model dim
constexpr int C      = 259;  // k/v channel dim
constexpr int E      = 32;   // neighbors
constexpr int NHEAD  = 8;
constexpr int NB     = 4;    // nodes per block
constexpr int WP     = 132;  // uint pitch per (nb,h) row of packed bf16 pairs
constexpr float SCALE = 0.17677669529663687f; // 1/sqrt(32)

__device__ __forceinline__ float dot4(float4 a, float4 b) {
    return a.x * b.x + a.y * b.y + a.z * b.z + a.w * b.w;
}
__device__ __forceinline__ unsigned pack_bf16(float lo, float hi) {
    unsigned bl = (__float_as_uint(lo) + 0x8000u) >> 16;
    unsigned bh = (__float_as_uint(hi) + 0x8000u) & 0xffff0000u;
    return bh | bl;
}
__device__ __forceinline__ float lo_bf(unsigned u) { return __uint_as_float(u << 16); }
__device__ __forceinline__ float hi_bf(unsigned u) { return __uint_as_float(u & 0xffff0000u); }

// (256,4): 64-VGPR target. Every phase below keeps <= ~40 live floats so the
// kernel actually fits (R3/R5/R6 spilled because P1/P5 m-outer held ~90 live).
__global__ __launch_bounds__(256, 4) void mha_neigh_kernel(
    const float* __restrict__ q, const float* __restrict__ kk, const float* __restrict__ vv,
    const float* __restrict__ Wq, const float* __restrict__ Wk,
    const float* __restrict__ Wv, const float* __restrict__ Wo,
    float* __restrict__ outp, int n)
{
    // 16896 + 4096 + 2048 = 23040 B -> 7 blocks/CU (28 waves) at 64 VGPR
    __shared__ __align__(16) unsigned w_p[NB * NHEAD * WP]; // q-stage -> w(bf16x2) -> vbar(bf16x2)
    __shared__ __align__(16) float    uni[NB * 256];        // qp -> simi -> out
    __shared__ __align__(16) unsigned att_p[NB * E * 4];    // att packed bf16x2 [nb][e][h/2]

    const int t    = threadIdx.x;
    const int wv   = t >> 6;
    const int lane = t & 63;
    const int dr   = lane >> 3;  // row-octet 0..7
    const int cs   = lane & 7;   // c-chunk 0..7
    const int n0   = blockIdx.x * NB;

    int node[NB];
    #pragma unroll
    for (int nb = 0; nb < NB; ++nb) {
        int nn = n0 + nb;
        node[nb] = (nn < n) ? nn : (n - 1);
    }

    // ---- P0: stage q into LDS (aliases w_p; dead before P2 writes w)
    float* q_st = (float*)w_p;
    #pragma unroll
    for (int nb = 0; nb < NB; ++nb) q_st[nb * 256 + t] = q[(size_t)node[nb] * H + t];
    __syncthreads();

    // ---- P1: qp[nb][row] = sum_c Wq[row][c] * q[nb][c]
    // p-outer (2-row unroll): ~28 live floats. q chunks are LDS broadcasts.
    {
        const float4* Wq4 = (const float4*)Wq;
        #pragma unroll 1
        for (int pp = 0; pp < 4; ++pp) {
            const int row0 = (2 * pp) * 32 + wv * 8 + dr;
            const int row1 = row0 + 32;
            float acc0[NB] = {}, acc1[NB] = {};
            #pragma unroll
            for (int m = 0; m < 8; ++m) {
                float4 wq0 = Wq4[(size_t)row0 * 64 + cs + 8 * m];
                float4 wq1 = Wq4[(size_t)row1 * 64 + cs + 8 * m];
                #pragma unroll
                for (int nb = 0; nb < NB; ++nb) {
                    float4 qv = *(const float4*)&q_st[nb * 256 + cs * 4 + 32 * m];
                    acc0[nb] += dot4(wq0, qv);
                    acc1[nb] += dot4(wq1, qv);
                }
            }
            #pragma unroll
            for (int off = 1; off <= 4; off <<= 1) {
                #pragma unroll
                for (int nb = 0; nb < NB; ++nb) {
                    acc0[nb] += __shfl_xor(acc0[nb], off, 64);
                    acc1[nb] += __shfl_xor(acc1[nb], off, 64);
                }
            }
            float v0 = (cs == 0) ? acc0[0] : (cs == 1) ? acc0[1] : (cs == 2) ? acc0[2] : acc0[3];
            float v1 = (cs == 0) ? acc1[0] : (cs == 1) ? acc1[1] : (cs == 2) ? acc1[2] : acc1[3];
            if (cs < 4) {
                uni[cs * 256 + row0] = v0;
                uni[cs * 256 + row1] = v1;
            }
        }
    }
    __syncthreads();   // qp visible; q_st (w_p alias) reads complete

    // ---- P2: w[nb][h][c] = sum_d qp[nb][h*32+d] * Wk[h*32+d][c]; pack bf16 pairs
    // qq-outer: 8 live accumulators; qp re-read per qq as LDS broadcast.
    {
        const int h  = t >> 5;
        const int c0 = t & 31;
        #pragma unroll 1
        for (int qq = 0; qq < 4; ++qq) {
            float accE[NB] = {}, accO[NB] = {};
            for (int d4 = 0; d4 < 8; ++d4) {
                float4 qp4[NB];
                #pragma unroll
                for (int nb = 0; nb < NB; ++nb)
                    qp4[nb] = *(const float4*)&uni[nb * 256 + h * 32 + d4 * 4];
                #pragma unroll
                for (int dd = 0; dd < 4; ++dd) {
                    const float* wkrow = Wk + (size_t)(h * 32 + d4 * 4 + dd) * C;
                    float2 wk2 = *(const float2*)&wkrow[2 * c0 + 64 * qq];
                    float q0 = (dd == 0) ? qp4[0].x : (dd == 1) ? qp4[0].y : (dd == 2) ? qp4[0].z : qp4[0].w;
                    float q1 = (dd == 0) ? qp4[1].x : (dd == 1) ? qp4[1].y : (dd == 2) ? qp4[1].z : qp4[1].w;
                    float q2 = (dd == 0) ? qp4[2].x : (dd == 1) ? qp4[2].y : (dd == 2) ? qp4[2].z : qp4[2].w;
                    float q3 = (dd == 0) ? qp4[3].x : (dd == 1) ? qp4[3].y : (dd == 2) ? qp4[3].z : qp4[3].w;
                    accE[0] += wk2.x * q0; accO[0] += wk2.y * q0;
                    accE[1] += wk2.x * q1; accO[1] += wk2.y * q1;
                    accE[2] += wk2.x * q2; accO[2] += wk2.y * q2;
                    accE[3] += wk2.x * q3; accO[3] += wk2.y * q3;
                }
            }
            #pragma unroll
            for (int nb = 0; nb < NB; ++nb)
                w_p[(nb * NHEAD + h) * WP + c0 + 32 * qq] = pack_bf16(accE[nb], accO[nb]);
        }
        if (c0 < 2) { // tail pairs: c = (256,257) / (258, 259->0)
            float accE[NB] = {}, accO[NB] = {};
            for (int d = 0; d < 32; ++d) {
                const float* wkrow = Wk + (size_t)(h * 32 + d) * C;
                float e0 = wkrow[256 + 2 * c0];
                float e1 = (c0 == 0) ? wkrow[257] : 0.0f;
                #pragma unroll
                for (int nb = 0; nb < NB; ++nb) {
                    float qpv = uni[nb * 256 + h * 32 + d];
                    accE[nb] += e0 * qpv;
                    accO[nb] += e1 * qpv;
                }
            }
            #pragma unroll
            for (int nb = 0; nb < NB; ++nb)
                w_p[(nb * NHEAD + h) * WP + 128 + c0] = pack_bf16(accE[nb], accO[nb]);
        }
    }
    __syncthreads();

    // ---- P3a: simi direct from global k; thread -> (e = t>>3, j = t&7); w from packed LDS
    {
        const int e = t >> 3;
        const int j = t & 7;
        #pragma unroll 2
        for (int nb = 0; nb < NB; ++nb) {
            const float* krow = kk + (size_t)node[nb] * (E * C) + (size_t)e * C;
            float acc[NHEAD] = {};
            #pragma unroll
            for (int m2 = 0; m2 < 4; ++m2) {
                float4 ka = *(const float4*)&krow[j * 8 + 64 * m2];
                float4 kb = *(const float4*)&krow[j * 8 + 64 * m2 + 4];
                const unsigned* wb = &w_p[(nb * NHEAD) * WP + j * 4 + 32 * m2];
                #pragma unroll
                for (int h = 0; h < NHEAD; ++h) {
                    uint4 wu = *(const uint4*)&wb[h * WP];
                    acc[h] += ka.x * lo_bf(wu.x) + ka.y * hi_bf(wu.x)
                            + ka.z * lo_bf(wu.y) + ka.w * hi_bf(wu.y)
                            + kb.x * lo_bf(wu.z) + kb.y * hi_bf(wu.z)
                            + kb.z * lo_bf(wu.w) + kb.w * hi_bf(wu.w);
                }
            }
            if (j == 0) { // tail c = 256..258
                float k0 = krow[256], k1 = krow[257], k2 = krow[258];
                #pragma unroll
                for (int h = 0; h < NHEAD; ++h) {
                    uint2 wt = *(const uint2*)&w_p[(nb * NHEAD + h) * WP + 128];
                    acc[h] += k0 * lo_bf(wt.x) + k1 * hi_bf(wt.x) + k2 * lo_bf(wt.y);
                }
            }
            #pragma unroll
            for (int h = 0; h < NHEAD; ++h) {
                float s = acc[h];
                s += __shfl_xor(s, 1, 64);
                s += __shfl_xor(s, 2, 64);
                s += __shfl_xor(s, 4, 64);
                acc[h] = s;
            }
            float myv = 0.0f;
            #pragma unroll
            for (int h = 0; h < NHEAD; ++h) myv = (j == h) ? acc[h] : myv;
            uni[nb * 256 + e * 8 + j] = myv * SCALE;   // simi slot [nb][e][h=j]
        }
    }
    __syncthreads();

    // ---- P3b: softmax over e per head; pack att as bf16 pairs [nb][e][h/2]
    {
        const int h   = t >> 5;
        const int e32 = t & 31;
        #pragma unroll
        for (int nb = 0; nb < NB; ++nb) {
            float s = uni[nb * 256 + e32 * 8 + h];
            float mx = s;
            #pragma unroll
            for (int off = 16; off >= 1; off >>= 1) mx = fmaxf(mx, __shfl_xor(mx, off, 64));
            float p = __expf(s - mx);
            float sum = p;
            #pragma unroll
            for (int off = 16; off >= 1; off >>= 1) sum += __shfl_xor(sum, off, 64);
            float att = p / sum;
            float oth = __shfl_xor(att, 32, 64);   // partner head (h even <-> h odd)
            if ((t & 32) == 0)
                att_p[nb * (E * 4) + e32 * 4 + (h >> 1)] = pack_bf16(att, oth);
        }
    }
    __syncthreads();

    // ---- P3c: vbar[nb][h][c] = sum_e att[e][h] * v[e][c]; thread owns c = t; pack to bf16
    {
        #pragma unroll 1
        for (int nb = 0; nb < NB; ++nb) {
            const float* vrow = vv + (size_t)node[nb] * (E * C);
            float acc[NHEAD] = {};
            #pragma unroll 8
            for (int e = 0; e < E; ++e) {
                uint4 au = *(const uint4*)&att_p[nb * (E * 4) + e * 4];
                float x = vrow[e * C + t];
                acc[0] += lo_bf(au.x) * x; acc[1] += hi_bf(au.x) * x;
                acc[2] += lo_bf(au.y) * x; acc[3] += hi_bf(au.y) * x;
                acc[4] += lo_bf(au.z) * x; acc[5] += hi_bf(au.z) * x;
                acc[6] += lo_bf(au.w) * x; acc[7] += hi_bf(au.w) * x;
            }
            #pragma unroll
            for (int h = 0; h < NHEAD; ++h) {
                float oth = __shfl_xor(acc[h], 1, 64);
                if ((t & 1) == 0)
                    w_p[(nb * NHEAD + h) * WP + (t >> 1)] = pack_bf16(acc[h], oth);
            }
            if (t < 4) { // tail c = 256..259 (259 -> 0)
                float a2[NHEAD] = {};
                if (t < 3) {
                    for (int e = 0; e < E; ++e) {
                        uint4 au = *(const uint4*)&att_p[nb * (E * 4) + e * 4];
                        float x2 = vrow[e * C + 256 + t];
                        a2[0] += lo_bf(au.x) * x2; a2[1] += hi_bf(au.x) * x2;
                        a2[2] += lo_bf(au.y) * x2; a2[3] += hi_bf(au.y) * x2;
                        a2[4] += lo_bf(au.z) * x2; a2[5] += hi_bf(au.z) * x2;
                        a2[6] += lo_bf(au.w) * x2; a2[7] += hi_bf(au.w) * x2;
                    }
                }
                #pragma unroll
                for (int h = 0; h < NHEAD; ++h) {
                    float oth = __shfl_xor(a2[h], 1, 64);
                    if ((t & 1) == 0)
                        w_p[(nb * NHEAD + h) * WP + 128 + (t >> 1)] = pack_bf16(a2[h], oth);
                }
            }
        }
    }
    __syncthreads();

    // ---- P4: out[nb][row] = sum_c vbar[nb][h][c] * Wv[row][c]; h = p per pass (~30 live)
    #pragma unroll 1
    for (int p = 0; p < 8; ++p) {
        const int row = p * 32 + wv * 8 + dr;
        const float* wvrow = Wv + (size_t)row * C;
        float a[NB] = {};
        #pragma unroll
        for (int m2 = 0; m2 < 4; ++m2) {
            float4 wa = *(const float4*)&wvrow[cs * 8 + 64 * m2];
            float4 wb = *(const float4*)&wvrow[cs * 8 + 64 * m2 + 4];
            #pragma unroll
            for (int nb = 0; nb < NB; ++nb) {
                uint4 vu = *(const uint4*)&w_p[(nb * NHEAD + p) * WP + cs * 4 + 32 * m2];
                a[nb] += wa.x * lo_bf(vu.x) + wa.y * hi_bf(vu.x)
                       + wa.z * lo_bf(vu.y) + wa.w * hi_bf(vu.y)
                       + wb.x * lo_bf(vu.z) + wb.y * hi_bf(vu.z)
                       + wb.z * lo_bf(vu.w) + wb.w * hi_bf(vu.w);
            }
        }
        if (cs == 0) { // tail c = 256..258
            float w0 = wvrow[256], w1 = wvrow[257], w2 = wvrow[258];
            #pragma unroll
            for (int nb = 0; nb < NB; ++nb) {
                uint2 vt = *(const uint2*)&w_p[(nb * NHEAD + p) * WP + 128];
                a[nb] += w0 * lo_bf(vt.x) + w1 * hi_bf(vt.x) + w2 * lo_bf(vt.y);
            }
        }
        #pragma unroll
        for (int off = 1; off <= 4; off <<= 1) {
            a[0] += __shfl_xor(a[0], off, 64);
            a[1] += __shfl_xor(a[1], off, 64);
            a[2] += __shfl_xor(a[2], off, 64);
            a[3] += __shfl_xor(a[3], off, 64);
        }
        float val = (cs == 0) ? a[0] : (cs == 1) ? a[1] : (cs == 2) ? a[2] : a[3];
        if (cs < 4) uni[cs * 256 + row] = val;  // out slot (simi dead)
    }
    __syncthreads();

    // ---- P5: final[nb][row] = sum_dd Wo[row][dd] * out[nb][dd]; p-outer (2-row unroll)
    {
        const float4* Wo4 = (const float4*)Wo;
        #pragma unroll 1
        for (int pp = 0; pp < 4; ++pp) {
            const int row0 = (2 * pp) * 32 + wv * 8 + dr;
            const int row1 = row0 + 32;
            float acc0[NB] = {}, acc1[NB] = {};
            #pragma unroll
            for (int m = 0; m < 8; ++m) {
                float4 wo0 = Wo4[(size_t)row0 * 64 + cs + 8 * m];
                float4 wo1 = Wo4[(size_t)row1 * 64 + cs + 8 * m];
                #pragma unroll
                for (int nb = 0; nb < NB; ++nb) {
                    float4 ov = *(const float4*)&uni[nb * 256 + cs * 4 + 32 * m];
                    acc0[nb] += dot4(wo0, ov);
                    acc1[nb] += dot4(wo1, ov);
                }
            }
            #pragma unroll
            for (int off = 1; off <= 4; off <<= 1) {
                #pragma unroll
                for (int nb = 0; nb < NB; ++nb) {
                    acc0[nb] += __shfl_xor(acc0[nb], off, 64);
                    acc1[nb] += __shfl_xor(acc1[nb], off, 64);
                }
            }
            float v0 = (cs == 0) ? acc0[0] : (cs == 1) ? acc0[1] : (cs == 2) ? acc0[2] : acc0[3];
            float v1 = (cs == 0) ? acc1[0] : (cs == 1) ? acc1[1] : (cs == 2) ? acc1[2] : acc1[3];
            if (cs < 4 && (n0 + cs) < n) {
                outp[(size_t)(n0 + cs) * H + row0] = v0;
                outp[(size_t)(n0 + cs) * H + row1] = v1;
            }
        }
    }
}

} // anonymous namespace

extern "C" void kernel_launch(void* const* d_in, const int* in_sizes, int n_in,
                              void* d_out, int out_size, void* d_ws, size_t ws_size,
                              hipStream_t stream) {
    const float* q  = (const float*)d_in[0];
    const float* k  = (const float*)d_in[1];
    const float* v  = (const float*)d_in[2];
    const float* Wq = (const float*)d_in[3];
    const float* Wk = (const float*)d_in[4];
    const float* Wv = (const float*)d_in[5];
    const float* Wo = (const float*)d_in[6];
    float* out = (float*)d_out;

    const int n = in_sizes[0] / H;            // 10000 nodes
    const int blocks = (n + NB - 1) / NB;     // 2500

    mha_neigh_kernel<<<dim3(blocks), dim3(256), 0, stream>>>(
        q, k, v, Wq, Wk, Wv, Wo, out, n);
}

// Round 8
// 348.496 us; speedup vs baseline: 2.9758x; 2.9758x over previous
//
#include <hip/hip_runtime.h>
#include <hip/hip_bf16.h>

namespace {

constexpr int H      = 256;  // model dim
constexpr int C      = 259;  // k/v channel dim
constexpr int E      = 32;   // neighbors
constexpr int NHEAD  = 8;
constexpr int NB     = 4;    // nodes per block
constexpr int WP     = 132;  // uint pitch per (nb,h) row of packed bf16 pairs
constexpr float SCALE = 0.17677669529663687f; // 1/sqrt(32)

__device__ __forceinline__ float dot4(float4 a, float4 b) {
    return a.x * b.x + a.y * b.y + a.z * b.z + a.w * b.w;
}
__device__ __forceinline__ unsigned pack_bf16(float lo, float hi) {
    unsigned bl = (__float_as_uint(lo) + 0x8000u) >> 16;
    unsigned bh = (__float_as_uint(hi) + 0x8000u) & 0xffff0000u;
    return bh | bl;
}
__device__ __forceinline__ float lo_bf(unsigned u) { return __uint_as_float(u << 16); }
__device__ __forceinline__ float hi_bf(unsigned u) { return __uint_as_float(u & 0xffff0000u); }

// Pressure discipline: the compiler batches ALL global loads of an unrolled
// body into flight at once (R1/R3/R5/R6/R7 spills). Rules here: outer loops
// unroll 1, global-load loops unroll <=2 (<=4 float4 in flight), LDS-read
// loops unroll <=4, acc arrays <=16 floats. Worst phase ~55 live regs -> fits
// the 64-VGPR target of (256,4); LDS 23 KB -> 7 blocks/CU (28 waves).
__global__ __launch_bounds__(256, 4) void mha_neigh_kernel(
    const float* __restrict__ q, const float* __restrict__ kk, const float* __restrict__ vv,
    const float* __restrict__ Wq, const float* __restrict__ Wk,
    const float* __restrict__ Wv, const float* __restrict__ Wo,
    float* __restrict__ outp, int n)
{
    __shared__ __align__(16) unsigned w_p[NB * NHEAD * WP]; // q-stage -> w(bf16x2) -> vbar(bf16x2)
    __shared__ __align__(16) float    uni[NB * 256];        // qp -> simi -> out
    __shared__ __align__(16) unsigned att_p[NB * E * 4];    // att packed bf16x2 [nb][e][h/2]

    const int t    = threadIdx.x;
    const int wv   = t >> 6;
    const int lane = t & 63;
    const int dr   = lane >> 3;  // row-octet 0..7
    const int cs   = lane & 7;   // c-chunk 0..7
    const int n0   = blockIdx.x * NB;

    int node[NB];
    #pragma unroll
    for (int nb = 0; nb < NB; ++nb) {
        int nn = n0 + nb;
        node[nb] = (nn < n) ? nn : (n - 1);
    }

    // ---- P0: stage q into LDS (aliases w_p; dead before P2 writes w)
    float* q_st = (float*)w_p;
    #pragma unroll
    for (int nb = 0; nb < NB; ++nb) q_st[nb * 256 + t] = q[(size_t)node[nb] * H + t];
    __syncthreads();

    // ---- P1: qp[nb][row] = sum_c Wq[row][c] * q[nb][c]
    // pp unroll 1; m unroll 2 -> max 4 float4 global loads in flight.
    {
        const float4* Wq4 = (const float4*)Wq;
        #pragma unroll 1
        for (int pp = 0; pp < 4; ++pp) {
            const int row0 = (2 * pp) * 32 + wv * 8 + dr;
            const int row1 = row0 + 32;
            float acc0[NB] = {}, acc1[NB] = {};
            #pragma unroll 2
            for (int m = 0; m < 8; ++m) {
                float4 wq0 = Wq4[(size_t)row0 * 64 + cs + 8 * m];
                float4 wq1 = Wq4[(size_t)row1 * 64 + cs + 8 * m];
                #pragma unroll
                for (int nb = 0; nb < NB; ++nb) {
                    float4 qv = *(const float4*)&q_st[nb * 256 + cs * 4 + 32 * m];
                    acc0[nb] += dot4(wq0, qv);
                    acc1[nb] += dot4(wq1, qv);
                }
            }
            #pragma unroll
            for (int off = 1; off <= 4; off <<= 1) {
                #pragma unroll
                for (int nb = 0; nb < NB; ++nb) {
                    acc0[nb] += __shfl_xor(acc0[nb], off, 64);
                    acc1[nb] += __shfl_xor(acc1[nb], off, 64);
                }
            }
            float v0 = (cs == 0) ? acc0[0] : (cs == 1) ? acc0[1] : (cs == 2) ? acc0[2] : acc0[3];
            float v1 = (cs == 0) ? acc1[0] : (cs == 1) ? acc1[1] : (cs == 2) ? acc1[2] : acc1[3];
            if (cs < 4) {
                uni[cs * 256 + row0] = v0;
                uni[cs * 256 + row1] = v1;
            }
        }
    }
    __syncthreads();   // qp visible; q_st (w_p alias) reads complete

    // ---- P2: w[nb][h][c] = sum_d qp[nb][h*32+d] * Wk[h*32+d][c]; pack bf16 pairs
    // qq unroll 1, d4 unroll 1 -> 4 float2 weight loads in flight max.
    {
        const int h  = t >> 5;
        const int c0 = t & 31;
        #pragma unroll 1
        for (int qq = 0; qq < 4; ++qq) {
            float accE[NB] = {}, accO[NB] = {};
            #pragma unroll 1
            for (int d4 = 0; d4 < 8; ++d4) {
                float4 qp4[NB];
                #pragma unroll
                for (int nb = 0; nb < NB; ++nb)
                    qp4[nb] = *(const float4*)&uni[nb * 256 + h * 32 + d4 * 4];
                #pragma unroll
                for (int dd = 0; dd < 4; ++dd) {
                    const float* wkrow = Wk + (size_t)(h * 32 + d4 * 4 + dd) * C;
                    float2 wk2 = *(const float2*)&wkrow[2 * c0 + 64 * qq];
                    float q0 = (dd == 0) ? qp4[0].x : (dd == 1) ? qp4[0].y : (dd == 2) ? qp4[0].z : qp4[0].w;
                    float q1 = (dd == 0) ? qp4[1].x : (dd == 1) ? qp4[1].y : (dd == 2) ? qp4[1].z : qp4[1].w;
                    float q2 = (dd == 0) ? qp4[2].x : (dd == 1) ? qp4[2].y : (dd == 2) ? qp4[2].z : qp4[2].w;
                    float q3 = (dd == 0) ? qp4[3].x : (dd == 1) ? qp4[3].y : (dd == 2) ? qp4[3].z : qp4[3].w;
                    accE[0] += wk2.x * q0; accO[0] += wk2.y * q0;
                    accE[1] += wk2.x * q1; accO[1] += wk2.y * q1;
                    accE[2] += wk2.x * q2; accO[2] += wk2.y * q2;
                    accE[3] += wk2.x * q3; accO[3] += wk2.y * q3;
                }
            }
            #pragma unroll
            for (int nb = 0; nb < NB; ++nb)
                w_p[(nb * NHEAD + h) * WP + c0 + 32 * qq] = pack_bf16(accE[nb], accO[nb]);
        }
        if (c0 < 2) { // tail pairs: c = (256,257) / (258, 259->0)
            float accE[NB] = {}, accO[NB] = {};
            #pragma unroll 2
            for (int d = 0; d < 32; ++d) {
                const float* wkrow = Wk + (size_t)(h * 32 + d) * C;
                float e0 = wkrow[256 + 2 * c0];
                float e1 = (c0 == 0) ? wkrow[257] : 0.0f;
                #pragma unroll
                for (int nb = 0; nb < NB; ++nb) {
                    float qpv = uni[nb * 256 + h * 32 + d];
                    accE[nb] += e0 * qpv;
                    accO[nb] += e1 * qpv;
                }
            }
            #pragma unroll
            for (int nb = 0; nb < NB; ++nb)
                w_p[(nb * NHEAD + h) * WP + 128 + c0] = pack_bf16(accE[nb], accO[nb]);
        }
    }
    __syncthreads();

    // ---- P3a: simi direct from global k; thread -> (e = t>>3, j = t&7)
    // nb unroll 1, m2 unroll 1 -> 2 float4 k-loads in flight; h unroll 4.
    {
        const int e = t >> 3;
        const int j = t & 7;
        #pragma unroll 1
        for (int nb = 0; nb < NB; ++nb) {
            const float* krow = kk + (size_t)node[nb] * (E * C) + (size_t)e * C;
            float acc[NHEAD] = {};
            #pragma unroll 1
            for (int m2 = 0; m2 < 4; ++m2) {
                float4 ka = *(const float4*)&krow[j * 8 + 64 * m2];
                float4 kb = *(const float4*)&krow[j * 8 + 64 * m2 + 4];
                const unsigned* wb = &w_p[(nb * NHEAD) * WP + j * 4 + 32 * m2];
                #pragma unroll 4
                for (int h = 0; h < NHEAD; ++h) {
                    uint4 wu = *(const uint4*)&wb[h * WP];
                    acc[h] += ka.x * lo_bf(wu.x) + ka.y * hi_bf(wu.x)
                            + ka.z * lo_bf(wu.y) + ka.w * hi_bf(wu.y)
                            + kb.x * lo_bf(wu.z) + kb.y * hi_bf(wu.z)
                            + kb.z * lo_bf(wu.w) + kb.w * hi_bf(wu.w);
                }
            }
            if (j == 0) { // tail c = 256..258
                float k0 = krow[256], k1 = krow[257], k2 = krow[258];
                #pragma unroll 4
                for (int h = 0; h < NHEAD; ++h) {
                    uint2 wt = *(const uint2*)&w_p[(nb * NHEAD + h) * WP + 128];
                    acc[h] += k0 * lo_bf(wt.x) + k1 * hi_bf(wt.x) + k2 * lo_bf(wt.y);
                }
            }
            #pragma unroll
            for (int h = 0; h < NHEAD; ++h) {
                float s = acc[h];
                s += __shfl_xor(s, 1, 64);
                s += __shfl_xor(s, 2, 64);
                s += __shfl_xor(s, 4, 64);
                acc[h] = s;
            }
            float myv = 0.0f;
            #pragma unroll
            for (int h = 0; h < NHEAD; ++h) myv = (j == h) ? acc[h] : myv;
            uni[nb * 256 + e * 8 + j] = myv * SCALE;   // simi slot [nb][e][h=j]
        }
    }
    __syncthreads();

    // ---- P3b: softmax over e per head; pack att as bf16 pairs [nb][e][h/2]
    {
        const int h   = t >> 5;
        const int e32 = t & 31;
        #pragma unroll 1
        for (int nb = 0; nb < NB; ++nb) {
            float s = uni[nb * 256 + e32 * 8 + h];
            float mx = s;
            #pragma unroll
            for (int off = 16; off >= 1; off >>= 1) mx = fmaxf(mx, __shfl_xor(mx, off, 64));
            float p = __expf(s - mx);
            float sum = p;
            #pragma unroll
            for (int off = 16; off >= 1; off >>= 1) sum += __shfl_xor(sum, off, 64);
            float att = p / sum;
            float oth = __shfl_xor(att, 32, 64);   // partner head (h even <-> h odd)
            if ((t & 32) == 0)
                att_p[nb * (E * 4) + e32 * 4 + (h >> 1)] = pack_bf16(att, oth);
        }
    }
    __syncthreads();

    // ---- P3c: vbar[nb][h][c] = sum_e att[e][h] * v[e][c]; thread owns c = t
    // e unroll 4 -> 4 scalar v-loads + 4 uint4 att reads in flight.
    {
        #pragma unroll 1
        for (int nb = 0; nb < NB; ++nb) {
            const float* vrow = vv + (size_t)node[nb] * (E * C);
            float acc[NHEAD] = {};
            #pragma unroll 4
            for (int e = 0; e < E; ++e) {
                uint4 au = *(const uint4*)&att_p[nb * (E * 4) + e * 4];
                float x = vrow[e * C + t];
                acc[0] += lo_bf(au.x) * x; acc[1] += hi_bf(au.x) * x;
                acc[2] += lo_bf(au.y) * x; acc[3] += hi_bf(au.y) * x;
                acc[4] += lo_bf(au.z) * x; acc[5] += hi_bf(au.z) * x;
                acc[6] += lo_bf(au.w) * x; acc[7] += hi_bf(au.w) * x;
            }
            #pragma unroll
            for (int h = 0; h < NHEAD; ++h) {
                float oth = __shfl_xor(acc[h], 1, 64);
                if ((t & 1) == 0)
                    w_p[(nb * NHEAD + h) * WP + (t >> 1)] = pack_bf16(acc[h], oth);
            }
            if (t < 4) { // tail c = 256..259 (259 -> 0)
                float a2[NHEAD] = {};
                if (t < 3) {
                    #pragma unroll 2
                    for (int e = 0; e < E; ++e) {
                        uint4 au = *(const uint4*)&att_p[nb * (E * 4) + e * 4];
                        float x2 = vrow[e * C + 256 + t];
                        a2[0] += lo_bf(au.x) * x2; a2[1] += hi_bf(au.x) * x2;
                        a2[2] += lo_bf(au.y) * x2; a2[3] += hi_bf(au.y) * x2;
                        a2[4] += lo_bf(au.z) * x2; a2[5] += hi_bf(au.z) * x2;
                        a2[6] += lo_bf(au.w) * x2; a2[7] += hi_bf(au.w) * x2;
                    }
                }
                #pragma unroll
                for (int h = 0; h < NHEAD; ++h) {
                    float oth = __shfl_xor(a2[h], 1, 64);
                    if ((t & 1) == 0)
                        w_p[(nb * NHEAD + h) * WP + 128 + (t >> 1)] = pack_bf16(a2[h], oth);
                }
            }
        }
    }
    __syncthreads();

    // ---- P4: out[nb][row] = sum_c vbar[nb][h][c] * Wv[row][c]; h = p per pass
    // p unroll 1; m2 unroll 2 -> 4 float4 weight loads in flight.
    #pragma unroll 1
    for (int p = 0; p < 8; ++p) {
        const int row = p * 32 + wv * 8 + dr;
        const float* wvrow = Wv + (size_t)row * C;
        float a[NB] = {};
        #pragma unroll 2
        for (int m2 = 0; m2 < 4; ++m2) {
            float4 wa = *(const float4*)&wvrow[cs * 8 + 64 * m2];
            float4 wb = *(const float4*)&wvrow[cs * 8 + 64 * m2 + 4];
            #pragma unroll
            for (int nb = 0; nb < NB; ++nb) {
                uint4 vu = *(const uint4*)&w_p[(nb * NHEAD + p) * WP + cs * 4 + 32 * m2];
                a[nb] += wa.x * lo_bf(vu.x) + wa.y * hi_bf(vu.x)
                       + wa.z * lo_bf(vu.y) + wa.w * hi_bf(vu.y)
                       + wb.x * lo_bf(vu.z) + wb.y * hi_bf(vu.z)
                       + wb.z * lo_bf(vu.w) + wb.w * hi_bf(vu.w);
            }
        }
        if (cs == 0) { // tail c = 256..258
            float w0 = wvrow[256], w1 = wvrow[257], w2 = wvrow[258];
            #pragma unroll
            for (int nb = 0; nb < NB; ++nb) {
                uint2 vt = *(const uint2*)&w_p[(nb * NHEAD + p) * WP + 128];
                a[nb] += w0 * lo_bf(vt.x) + w1 * hi_bf(vt.x) + w2 * lo_bf(vt.y);
            }
        }
        #pragma unroll
        for (int off = 1; off <= 4; off <<= 1) {
            a[0] += __shfl_xor(a[0], off, 64);
            a[1] += __shfl_xor(a[1], off, 64);
            a[2] += __shfl_xor(a[2], off, 64);
            a[3] += __shfl_xor(a[3], off, 64);
        }
        float val = (cs == 0) ? a[0] : (cs == 1) ? a[1] : (cs == 2) ? a[2] : a[3];
        if (cs < 4) uni[cs * 256 + row] = val;  // out slot (simi dead)
    }
    __syncthreads();

    // ---- P5: final[nb][row] = sum_dd Wo[row][dd] * out[nb][dd]; pp unroll 1, m unroll 2
    {
        const float4* Wo4 = (const float4*)Wo;
        #pragma unroll 1
        for (int pp = 0; pp < 4; ++pp) {
            const int row0 = (2 * pp) * 32 + wv * 8 + dr;
            const int row1 = row0 + 32;
            float acc0[NB] = {}, acc1[NB] = {};
            #pragma unroll 2
            for (int m = 0; m < 8; ++m) {
                float4 wo0 = Wo4[(size_t)row0 * 64 + cs + 8 * m];
                float4 wo1 = Wo4[(size_t)row1 * 64 + cs + 8 * m];
                #pragma unroll
                for (int nb = 0; nb < NB; ++nb) {
                    float4 ov = *(const float4*)&uni[nb * 256 + cs * 4 + 32 * m];
                    acc0[nb] += dot4(wo0, ov);
                    acc1[nb] += dot4(wo1, ov);
                }
            }
            #pragma unroll
            for (int off = 1; off <= 4; off <<= 1) {
                #pragma unroll
                for (int nb = 0; nb < NB; ++nb) {
                    acc0[nb] += __shfl_xor(acc0[nb], off, 64);
                    acc1[nb] += __shfl_xor(acc1[nb], off, 64);
                }
            }
            float v0 = (cs == 0) ? acc0[0] : (cs == 1) ? acc0[1] : (cs == 2) ? acc0[2] : acc0[3];
            float v1 = (cs == 0) ? acc1[0] : (cs == 1) ? acc1[1] : (cs == 2) ? acc1[2] : acc1[3];
            if (cs < 4 && (n0 + cs) < n) {
                outp[(size_t)(n0 + cs) * H + row0] = v0;
                outp[(size_t)(n0 + cs) * H + row1] = v1;
            }
        }
    }
}

} // anonymous namespace

extern "C" void kernel_launch(void* const* d_in, const int* in_sizes, int n_in,
                              void* d_out, int out_size, void* d_ws, size_t ws_size,
                              hipStream_t stream) {
    const float* q  = (const float*)d_in[0];
    const float* k  = (const float*)d_in[1];
    const float* v  = (const float*)d_in[2];
    const float* Wq = (const float*)d_in[3];
    const float* Wk = (const float*)d_in[4];
    const float* Wv = (const float*)d_in[5];
    const float* Wo = (const float*)d_in[6];
    float* out = (float*)d_out;

    const int n = in_sizes[0] / H;            // 10000 nodes
    const int blocks = (n + NB - 1) / NB;     // 2500

    mha_neigh_kernel<<<dim3(blocks), dim3(256), 0, stream>>>(
        q, k, v, Wq, Wk, Wv, Wo, out, n);
}